// Round 1
// 214.718 us; speedup vs baseline: 1.0153x; 1.0153x over previous
//
#include <hip/hip_runtime.h>

#define BB 4
#define NN 16384
#define SS 4096
#define CIN 256
#define COUT 256

#define SC 8                  // s-chunks for knn
#define SCS (SS / SC)         // 512 points per chunk
// Uniform fused grid: 1024 blocks, each = 1 knn unit (32nb x 8ch x 4b) AND
// 1 gemm tile (4o x 64s x 4b). Order alternated per (bid>>8) so each CU
// (which gets bids {c, c+256, c+512, c+768}) always mixes knn-phase waves
// (VALU-dense f64) with gemm-phase waves (staging stalls) -> no drained tail.
#define FUSEB 1024

typedef float v2f __attribute__((ext_vector_type(2)));
typedef float v4f __attribute__((ext_vector_type(4)));

__device__ __forceinline__ unsigned short f2bf(float f) {   // RNE float->bf16
    unsigned u = __float_as_uint(f);
    u += 0x7FFF + ((u >> 16) & 1);
    return (unsigned short)(u >> 16);
}
__device__ __forceinline__ float bf2f(unsigned short h) {
    return __uint_as_float((unsigned)h << 16);
}

// Packed key: kd = (double)e + 640.0 lies in binade [512,1024) (e in (-78,78)),
// so ulp = 2^-43 fixed; low 12 mantissa bits replaced by s => e quantized at
// 2^-31 absolute (flip prob ~1e-4 total) and ordering == (e, s) lexicographic
// == reference stable top_k tie-break. Insert = select-free min/max network.
__device__ __forceinline__ double pack_key(float e, unsigned gs) {
    double kd = (double)e + 640.0;
    unsigned long long b = __double_as_longlong(kd);
    b = (b & 0xFFFFFFFFFFFFF000ULL) | (unsigned long long)gs;
    return __longlong_as_double((long long)b);
}
__device__ __forceinline__ void insert_key(double& k0, double& k1, double& k2,
                                           double x) {
    double m  = fmax(k0, x);
    k0 = fmin(k0, x);
    double m2 = fmax(k1, m);
    k1 = fmin(k1, m);
    k2 = fmin(k2, m2);
}

// v_pk_fma_f32: D = S0*S1 + S2 per 32-bit half; op_sel/[_hi] pick which half
// of each 64-bit source feeds the lo/hi op. Used to (a) broadcast a scalar
// into both halves and (b) pack query-A (lo) / query-B (hi) distance chains.
// Results are IEEE f32 fma per half == fmaf -> bit-identical to scalar code.
#define PK_LO(acc, ap, bw)                                                     \
    asm("v_pk_fma_f32 %0, %1, %2, %0 op_sel:[0,0,0] op_sel_hi:[0,1,1]"         \
        : "+v"(acc) : "v"(ap), "v"(bw))
#define PK_HI(acc, ap, bw)                                                     \
    asm("v_pk_fma_f32 %0, %1, %2, %0 op_sel:[1,0,0] op_sel_hi:[1,1,1]"         \
        : "+v"(acc) : "v"(ap), "v"(bw))

// ---------------------------------------------------------------------------
// knn phase: partial 3-NN for (nb, ch, b), NPT=2 (queries A=lo, B=hi packed).
// Inner loop per candidate: 1 ds_read_b128 + 3 v_pk_fma_f32 + 2 key-builds +
// 2x 5 f64 min/max. e is computed z->y->x, same order as before -> bitwise
// identical keys.
// ---------------------------------------------------------------------------
__device__ __forceinline__ void knn_phase(int bid, int t, float* smem,
                                          const float* __restrict__ xyz1,
                                          const float* __restrict__ xyz2,
                                          unsigned long long* __restrict__ pk) {
    int nb = bid & 31;
    int ch = (bid >> 5) & 7;
    int b  = bid >> 8;
    int s0 = ch * SCS;

    float4* smv = (float4*)smem;
    const float* x2 = xyz2 + (size_t)b * 3 * SS;
    __syncthreads();   // smem reuse guard (needed when gemm ran first)
    for (int i = t; i < SCS; i += 256) {
        float px = x2[s0 + i];
        float py = x2[SS + s0 + i];
        float pz = x2[2 * SS + s0 + i];
        smv[i] = make_float4(px, py, pz, fmaf(px, px, fmaf(py, py, pz * pz)));
    }
    __syncthreads();

    int n0  = nb * 512 + t;
    int n1q = n0 + 256;
    const float* xb = xyz1 + (size_t)b * 3 * NN;
    float ax = xb[n0],  ay = xb[NN + n0],  az = xb[2 * NN + n0];
    float bx = xb[n1q], by = xb[NN + n1q], bz = xb[2 * NN + n1q];
    v2f XX = {-2.0f * ax, -2.0f * bx};
    v2f YY = {-2.0f * ay, -2.0f * by};
    v2f ZZ = {-2.0f * az, -2.0f * bz};

    double AK0 = 1023.0, AK1 = 1023.0, AK2 = 1023.0;
    double BK0 = 1023.0, BK1 = 1023.0, BK2 = 1023.0;

#pragma unroll 8
    for (int s = 0; s < SCS; ++s) {
        v4f p = *(const v4f*)(smem + 4 * s);
        v2f pxy = __builtin_shufflevector(p, p, 0, 1);   // {x, y}
        v2f pzw = __builtin_shufflevector(p, p, 2, 3);   // {z, |p|^2}
        v2f e2;
        // e = z*zm2 + w   (lo: query A, hi: query B; z,w broadcast via op_sel)
        asm("v_pk_fma_f32 %0, %1, %2, %3 op_sel:[0,0,1] op_sel_hi:[0,1,1]"
            : "=v"(e2) : "v"(pzw), "v"(ZZ), "v"(pzw));
        // e = y*ym2 + e
        asm("v_pk_fma_f32 %0, %1, %2, %0 op_sel:[1,0,0] op_sel_hi:[1,1,1]"
            : "+v"(e2) : "v"(pxy), "v"(YY));
        // e = x*xm2 + e
        asm("v_pk_fma_f32 %0, %1, %2, %0 op_sel:[0,0,0] op_sel_hi:[0,1,1]"
            : "+v"(e2) : "v"(pxy), "v"(XX));
        unsigned gs = (unsigned)(s0 + s);
        insert_key(AK0, AK1, AK2, pack_key(e2.x, gs));
        insert_key(BK0, BK1, BK2, pack_key(e2.y, gs));
    }

    // layout [ch][b][j][n], u64 keys (coalesced 8B/lane)
    size_t cb = (size_t)(ch * BB + b) * 3;
    pk[(cb + 0) * NN + n0]  = (unsigned long long)__double_as_longlong(AK0);
    pk[(cb + 1) * NN + n0]  = (unsigned long long)__double_as_longlong(AK1);
    pk[(cb + 2) * NN + n0]  = (unsigned long long)__double_as_longlong(AK2);
    pk[(cb + 0) * NN + n1q] = (unsigned long long)__double_as_longlong(BK0);
    pk[(cb + 1) * NN + n1q] = (unsigned long long)__double_as_longlong(BK1);
    pk[(cb + 2) * NN + n1q] = (unsigned long long)__double_as_longlong(BK2);
}

// ---------------------------------------------------------------------------
// gemm phase: 64s x 64o tile, 4x4 micro via 8 v_pk_fma_f32 per cc (was 16
// v_fma_f32). acc2[p] = {q0,q1},{q2,q3}; a broadcast lo/hi via op_sel.
// ---------------------------------------------------------------------------
__device__ __forceinline__ void gemm_phase(int bid, int t, float* smem,
                                           const float* __restrict__ P,
                                           const float* __restrict__ W,
                                           const float* __restrict__ bias,
                                           unsigned short* __restrict__ Gh) {
    int o0 = (bid & 3) * 64;
    int s0 = ((bid >> 2) & 63) * 64;
    int b  = bid >> 8;
    float* sP = smem;              // 16 x 64
    float* sW = smem + 1024;       // 16 x 68 (padded)
    int i = t & 15;
    int j = t >> 4;

    v2f acc2[4][2];
#pragma unroll
    for (int p = 0; p < 4; ++p) {
        acc2[p][0] = (v2f){0.f, 0.f};
        acc2[p][1] = (v2f){0.f, 0.f};
    }

    const float* Pb = P + (size_t)b * CIN * SS;

    for (int c0 = 0; c0 < CIN; c0 += 16) {
        __syncthreads();
        {
            int col = t & 63;
            int r0r = t >> 6;
#pragma unroll
            for (int r = 0; r < 4; ++r) {
                int row = r0r + r * 4;
                sP[row * 64 + col] = Pb[(size_t)(c0 + row) * SS + s0 + col];
            }
        }
        {
            int cc = t & 15;
            int obase = t >> 4;
#pragma unroll
            for (int r = 0; r < 4; ++r) {
                int oo = obase + 16 * r;
                sW[cc * 68 + oo] = W[(size_t)(o0 + oo) * CIN + c0 + cc];
            }
        }
        __syncthreads();

#pragma unroll
        for (int cc = 0; cc < 16; ++cc) {
            v4f a  = *(const v4f*)&sP[cc * 64 + i * 4];
            v4f bv = *(const v4f*)&sW[cc * 68 + j * 4];
            v2f a01 = __builtin_shufflevector(a, a, 0, 1);
            v2f a23 = __builtin_shufflevector(a, a, 2, 3);
            v2f b01 = __builtin_shufflevector(bv, bv, 0, 1);
            v2f b23 = __builtin_shufflevector(bv, bv, 2, 3);
            PK_LO(acc2[0][0], a01, b01); PK_LO(acc2[0][1], a01, b23);  // a.x
            PK_HI(acc2[1][0], a01, b01); PK_HI(acc2[1][1], a01, b23);  // a.y
            PK_LO(acc2[2][0], a23, b01); PK_LO(acc2[2][1], a23, b23);  // a.z
            PK_HI(acc2[3][0], a23, b01); PK_HI(acc2[3][1], a23, b23);  // a.w
        }
    }

    float b0 = bias[o0 + j * 4 + 0];
    float b1 = bias[o0 + j * 4 + 1];
    float b2 = bias[o0 + j * 4 + 2];
    float b3 = bias[o0 + j * 4 + 3];
#pragma unroll
    for (int p = 0; p < 4; ++p) {
        ushort4 v;
        v.x = f2bf(acc2[p][0].x + b0);
        v.y = f2bf(acc2[p][0].y + b1);
        v.z = f2bf(acc2[p][1].x + b2);
        v.w = f2bf(acc2[p][1].y + b3);
        size_t off = ((size_t)b * SS + s0 + i * 4 + p) * COUT + o0 + j * 4;
        *(ushort4*)&Gh[off] = v;
    }
}

// ---------------------------------------------------------------------------
// Fused kernel: every block does BOTH a knn unit and a gemm tile (uniform
// duration -> no drained-gemm tail). Order alternated by (bid>>8)&1 so each
// CU co-schedules knn-phase and gemm-phase waves.
// ---------------------------------------------------------------------------
__global__ __launch_bounds__(256) void k_fused(const float* __restrict__ xyz1,
                                               const float* __restrict__ xyz2,
                                               const float* __restrict__ P,
                                               const float* __restrict__ W,
                                               const float* __restrict__ bias,
                                               unsigned short* __restrict__ Gh,
                                               unsigned long long* __restrict__ pk) {
    __shared__ float smem[2112];   // 8.25 KB: knn 512 float4; gemm sP+sW
    int bid = blockIdx.x;
    int t   = threadIdx.x;

    if (((bid >> 8) & 1) == 0) {
        knn_phase(bid, t, smem, xyz1, xyz2, pk);
        gemm_phase(bid, t, smem, P, W, bias, Gh);
    } else {
        gemm_phase(bid, t, smem, P, W, bias, Gh);
        knn_phase(bid, t, smem, xyz1, xyz2, pk);
    }
}

// ---------------------------------------------------------------------------
// Merge: fold 24 packed keys per query via the same select-free network
// (order-independent: keys are globally ordered incl. index tie-break),
// recompute |p1|^2 from xyz1, decode {d, s}, weights -> wi4/gi4.
// ---------------------------------------------------------------------------
__global__ __launch_bounds__(256) void k_merge(const unsigned long long* __restrict__ pk,
                                               const float* __restrict__ xyz1,
                                               float4* __restrict__ wi4,
                                               int4* __restrict__ gi4) {
    int b = blockIdx.y;
    int n = blockIdx.x * 256 + threadIdx.x;

    double k0 = 1023.0, k1 = 1023.0, k2 = 1023.0;
#pragma unroll
    for (int ch = 0; ch < SC; ++ch) {
        size_t cb = (size_t)(ch * BB + b) * 3;
#pragma unroll
        for (int j = 0; j < 3; ++j) {
            double x = __longlong_as_double(
                (long long)pk[(cb + j) * NN + n]);
            insert_key(k0, k1, k2, x);
        }
    }

    const float* xb = xyz1 + (size_t)b * 3 * NN;
    float qx = xb[n], qy = xb[NN + n], qz = xb[2 * NN + n];
    float n1 = fmaf(qx, qx, fmaf(qy, qy, qz * qz));

    unsigned long long u0 = (unsigned long long)__double_as_longlong(k0);
    unsigned long long u1 = (unsigned long long)__double_as_longlong(k1);
    unsigned long long u2 = (unsigned long long)__double_as_longlong(k2);
    float e0 = (float)(__longlong_as_double((long long)(u0 & ~0xFFFULL)) - 640.0);
    float e1 = (float)(__longlong_as_double((long long)(u1 & ~0xFFFULL)) - 640.0);
    float e2 = (float)(__longlong_as_double((long long)(u2 & ~0xFFFULL)) - 640.0);
    float d0 = e0 + n1, d1 = e1 + n1, d2 = e2 + n1;

    float r0 = 1.0f / (d0 + 1e-8f);
    float r1 = 1.0f / (d1 + 1e-8f);
    float r2 = 1.0f / (d2 + 1e-8f);
    float inv = 1.0f / (r0 + r1 + r2);
    size_t q = (size_t)b * NN + n;
    wi4[q] = make_float4(r0 * inv, r1 * inv, r2 * inv, 0.f);
    gi4[q] = make_int4((int)(u0 & 0xFFFULL), (int)(u1 & 0xFFFULL),
                       (int)(u2 & 0xFFFULL), 0);
}

// ---------------------------------------------------------------------------
// Output: unchanged (XCD-swizzled flat grid, 64q x 64ch blocks,
// 4-query/wave MLP gather, stride-68 tile, coalesced stores).
// ---------------------------------------------------------------------------
__global__ __launch_bounds__(256) void k_out(const unsigned short* __restrict__ Gh,
                                             const float4* __restrict__ wi4,
                                             const int4* __restrict__ gi4,
                                             float* __restrict__ out) {
    __shared__ float  tile[64 * 68];   // 17.4 KB
    __shared__ float4 swv[64];
    __shared__ int4   siv[64];
    int bid  = blockIdx.x;
    int x    = bid & 7;                // XCD slot (blockIdx % 8 round-robin)
    int b    = x >> 1;                 // 2 XCDs per batch
    int local = (bid >> 3) + (x & 1) * 512;   // 0..1023 per batch
    int nb   = local & 255;            // 256 n-blocks
    int oc   = local >> 8;             // 4 o-chunks
    int n0   = nb * 64;
    int o0   = oc * 64;
    int t    = threadIdx.x;
    int wave = t >> 6;
    int lane = t & 63;
    int qg   = lane >> 4;     // query-in-group 0..3
    int c16  = lane & 15;     // channel quad 0..15

    if (t < 64) {
        size_t q = (size_t)b * NN + n0 + t;
        swv[t] = wi4[q];
        siv[t] = gi4[q];
    }
    __syncthreads();

    const unsigned short* Gb = Gh + (size_t)b * SS * COUT;

#pragma unroll
    for (int pass = 0; pass < 4; ++pass) {
        int q = pass * 16 + wave * 4 + qg;
        float4 wv = swv[q];
        int4   iv = siv[q];
        int co = o0 + c16 * 4;
        ushort4 a0 = *(const ushort4*)(Gb + (size_t)iv.x * COUT + co);
        ushort4 a1 = *(const ushort4*)(Gb + (size_t)iv.y * COUT + co);
        ushort4 a2 = *(const ushort4*)(Gb + (size_t)iv.z * COUT + co);
        float4 v;
        v.x = fmaf(wv.x, bf2f(a0.x), fmaf(wv.y, bf2f(a1.x), wv.z * bf2f(a2.x)));
        v.y = fmaf(wv.x, bf2f(a0.y), fmaf(wv.y, bf2f(a1.y), wv.z * bf2f(a2.y)));
        v.z = fmaf(wv.x, bf2f(a0.z), fmaf(wv.y, bf2f(a1.z), wv.z * bf2f(a2.z)));
        v.w = fmaf(wv.x, bf2f(a0.w), fmaf(wv.y, bf2f(a1.w), wv.z * bf2f(a2.w)));
        *(float4*)&tile[q * 68 + c16 * 4] = v;
    }
    __syncthreads();

    float* obase = out + ((size_t)b * COUT + o0) * NN + n0 + lane;
#pragma unroll
    for (int g = 0; g < 4; ++g) {
        int c = wave * 16 + g * 4;
        float4 v = *(const float4*)&tile[lane * 68 + c];
        obase[(size_t)(c + 0) * NN] = v.x;
        obase[(size_t)(c + 1) * NN] = v.y;
        obase[(size_t)(c + 2) * NN] = v.z;
        obase[(size_t)(c + 3) * NN] = v.w;
    }
}

// ---------------------------------------------------------------------------
extern "C" void kernel_launch(void* const* d_in, const int* in_sizes, int n_in,
                              void* d_out, int out_size, void* d_ws, size_t ws_size,
                              hipStream_t stream) {
    const float* xyz1    = (const float*)d_in[0];   // [B,3,N]
    const float* xyz2    = (const float*)d_in[1];   // [B,3,S]
    const float* points2 = (const float*)d_in[2];   // [B,CIN,S]
    const float* W       = (const float*)d_in[3];   // [COUT,CIN]
    const float* bias    = (const float*)d_in[4];   // [COUT]
    float* out = (float*)d_out;                     // [B,COUT,N]

    char* ws = (char*)d_ws;
    // workspace layout (bytes), total ~23 MB:
    //   pk  : 0        .. 12,582,912  ([SC][B][3][N] u64 packed keys)
    //   Gh  : 12582912 .. 20,971,520  ([B][S][COUT] bf16)
    //   wi4 : 20971520 .. 22,020,096  ([B][N] float4)
    //   gi4 : 22020096 .. 23,068,672  ([B][N] int4)
    unsigned long long* pk  = (unsigned long long*)(ws);
    unsigned short*     Gh  = (unsigned short*)(ws + 12582912);
    float4*             wi4 = (float4*)(ws + 20971520);
    int4*               gi4 = (int4*)(ws + 22020096);

    k_fused<<<dim3(FUSEB), 256, 0, stream>>>(xyz1, xyz2, points2, W, bias,
                                             Gh, pk);
    k_merge<<<dim3(NN / 256, BB), 256, 0, stream>>>(pk, xyz1, wi4, gi4);
    k_out<<<dim3(4096), 256, 0, stream>>>(Gh, wi4, gi4, out);
}